// Round 1
// 452.772 us; speedup vs baseline: 1.1459x; 1.1459x over previous
//
#include <hip/hip_runtime.h>

#define HW_  262144     // 512*512
#define C_   64
#define HID_ 128
#define K_   16
#define B_   4
#define NPIX (B_*HW_)   // 1048576
#define NSLICE 8        // accum contention-spreading slices

typedef __attribute__((ext_vector_type(8)))  short bf16x8;   // 8 bf16 = 4 VGPR
typedef __attribute__((ext_vector_type(16))) float f32x16;   // 32x32 C/D frag

// ---------- fast-path ws byte layout ----------
// [0, 8192)         accum slices: NSLICE x [b][k][4] fp32  (2048 floats)
// [8192, 8960)      palette fp32 [b][k][3]
// [10240, 43008)    W1 A-frags  (m,s)x{hi,lo}: 32 frags x 1KB  (bf16)
// [43008, 59392)    W2 A-frags  (t)x{hi,lo}:   16 frags x 1KB  (bf16, k>=16 zero-pad)
// [59392, ...)      labels, NPIX int
#define PALF_FLT 2048
#define W1F_BYTE 10240
#define W2F_BYTE 43008
#define LBL_BYTE 59392
#define WS_NEED_FAST ((size_t)LBL_BYTE + (size_t)NPIX*4)

__device__ __forceinline__ unsigned short f2bf(float x) {       // RNE fp32->bf16
    unsigned u = __float_as_uint(x);
    unsigned r = u + 0x7FFFu + ((u >> 16) & 1u);
    return (unsigned short)(r >> 16);
}
__device__ __forceinline__ float bf2f(unsigned short h) {
    return __uint_as_float(((unsigned)h) << 16);
}
__device__ __forceinline__ f32x16 mfma32(bf16x8 a, bf16x8 b, f32x16 c) {
    return __builtin_amdgcn_mfma_f32_32x32x16_bf16(a, b, c, 0, 0, 0);
}

// ================= fast path =================

// grid 48 x 256: zero accum slices + build W1/W2 frags (hi/lo split).
__global__ __launch_bounds__(256) void prep_fast(
    const float* __restrict__ W1, const float* __restrict__ W2,
    float* __restrict__ wsf)
{
    int gi = blockIdx.x*256 + threadIdx.x;
    if (gi < NSLICE*256) wsf[gi] = 0.0f;                // accum slices
    unsigned short* w1f = (unsigned short*)((char*)wsf + W1F_BYTE);
    unsigned short* w2f = (unsigned short*)((char*)wsf + W2F_BYTE);
    if (gi < 8192) {                                    // W1 frag elem
        int j = gi & 7, l = (gi >> 3) & 63, s = (gi >> 9) & 3, m = (gi >> 11) & 3;
        int o = 32*m + (l & 31);
        int c = 16*s + 8*(l >> 5) + j;
        float w  = W1[o*C_ + c];
        unsigned short hi = f2bf(w);
        unsigned short lo = f2bf(w - bf2f(hi));
        int base = ((m*4 + s)*2)*512 + l*8 + j;
        w1f[base]       = hi;
        w1f[base + 512] = lo;
    } else if (gi < 12288) {                            // W2 frag elem
        int i = gi - 8192;
        int j = i & 7, l = (i >> 3) & 63, t = (i >> 9) & 7;
        int k = l & 31;
        int o = 16*t + 8*(l >> 5) + j;
        float w = (k < K_) ? W2[k*HID_ + o] : 0.0f;
        unsigned short hi = f2bf(w);
        unsigned short lo = f2bf(w - bf2f(hi));
        int base = (t*2)*512 + l*8 + j;
        w2f[base]       = hi;
        w2f[base + 512] = lo;
    }
}

// 128 px / block (4 waves x 32 px). Split-bf16 MFMA MLP.
// Layer-2 interleaved into the layer-1 m-loop: only ONE layer-1 C-frag (16 regs)
// lives at a time instead of four (64), cutting total reg footprint ~148 -> ~100
// so 5 waves/SIMD fit (was 3). MFMA accumulation order is bitwise identical to
// the previous (validated) version: per m, s ascending; acc2 gets tg ascending.
__global__ __launch_bounds__(256, 5) void mlp_mfma(
    const float* __restrict__ feat, const float* __restrict__ img,
    const float* __restrict__ b1,
    const unsigned short* __restrict__ w1f, const unsigned short* __restrict__ w2f,
    float* __restrict__ m_out, float* __restrict__ accum, int* __restrict__ labels)
{
    __shared__ float b1s[HID_];
    __shared__ float bins[K_*4];

    int t = threadIdx.x, lane = t & 63, w = t >> 6;
    int col = lane & 31, half = lane >> 5;
    if (t < HID_) b1s[t] = b1[t];
    if (t < K_*4) bins[t] = 0.0f;
    __syncthreads();

    int blk = blockIdx.x;
    int b   = blk >> 11;                       // 2048 blocks per batch
    int px  = (blk & 2047)*128 + w*32 + col;
    const float* fb = feat + ((size_t)b*C_ << 18) + px;

    // hoist ALL 32 feat loads first: full vmcnt overlap
    float fv[32];
#pragma unroll
    for (int s = 0; s < 4; ++s)
#pragma unroll
        for (int j = 0; j < 8; ++j)
            fv[s*8 + j] = fb[(size_t)(16*s + 8*half + j) << 18];

    bf16x8 bh[4], bl[4];
#pragma unroll
    for (int s = 0; s < 4; ++s)
#pragma unroll
        for (int j = 0; j < 8; ++j) {
            float x = fv[s*8 + j];
            unsigned short hi = f2bf(x);
            bh[s][j] = (short)hi;
            bl[s][j] = (short)f2bf(x - bf2f(hi));
        }

    const bf16x8* w1v = (const bf16x8*)w1f;
    const bf16x8* w2v = (const bf16x8*)w2f;
    f32x16 acc2 = 0.0f;

#pragma unroll
    for (int m = 0; m < 4; ++m) {
        // ---- layer 1, rows o = 32m..32m+31 (split-bf16, 3-term) ----
        f32x16 accm = 0.0f;
#pragma unroll
        for (int s = 0; s < 4; ++s) {
            const bf16x8* p = w1v + ((m*4 + s)*2)*64 + lane;
            bf16x8 ah = p[0];      // hi frag
            bf16x8 al = p[64];     // lo frag
            accm = mfma32(ah, bh[s], accm);
            accm = mfma32(al, bh[s], accm);
            accm = mfma32(ah, bl[s], accm);
        }
        // ---- layer 2 for the two tile-groups that consume this m ----
        // C-frag: lane(col,half') reg r holds o = 32m + (r&3) + 8*(r>>2) + 4*half'.
        // B-frag: lane(col,h) elem j needs o = 16tg + 8h + j.
#pragma unroll
        for (int sub = 0; sub < 2; ++sub) {
            int tg = 2*m + sub;
            unsigned pk[8];
#pragma unroll
            for (int i = 0; i < 8; ++i) {
                int r = 8*sub + i;
                int o = 32*m + (i & 3) + 16*sub + 8*(i >> 2) + 4*half;
                float hv = fmaxf(accm[r] + b1s[o], 0.0f);
                unsigned short hi = f2bf(hv);
                unsigned short lo = f2bf(hv - bf2f(hi));
                pk[i] = ((unsigned)hi) | (((unsigned)lo) << 16);
            }
            bf16x8 bh2, bl2;
#pragma unroll
            for (int j = 0; j < 4; ++j) {
                unsigned ov = half ? pk[j+4] : pk[j];     // own kept value
                unsigned sv = half ? pk[j]   : pk[j+4];   // value partner needs
                unsigned rv = (unsigned)__shfl_xor((int)sv, 32);
                unsigned lowsrc  = half ? rv : ov;        // half'==0 source -> B[j]
                unsigned highsrc = half ? ov : rv;        // half'==1 source -> B[j+4]
                bh2[j]   = (short)(lowsrc  & 0xffffu);
                bl2[j]   = (short)(lowsrc  >> 16);
                bh2[j+4] = (short)(highsrc & 0xffffu);
                bl2[j+4] = (short)(highsrc >> 16);
            }
            const bf16x8* p2 = w2v + (tg*2)*64 + lane;
            bf16x8 ah2 = p2[0];
            bf16x8 al2 = p2[64];
            acc2 = mfma32(ah2, bh2, acc2);
            acc2 = mfma32(al2, bh2, acc2);
            acc2 = mfma32(ah2, bl2, acc2);
        }
    }

    // ---------- softmax(1e4*logits) + argmax; valid k rows are regs 0..7 ----------
    float lg[8]; int kk[8];
#pragma unroll
    for (int r = 0; r < 8; ++r) {
        lg[r] = acc2[r];
        kk[r] = (r & 3) + 8*(r >> 2) + 4*half;    // ascending within lane
    }
    float mx = lg[0]; int ki = kk[0];
#pragma unroll
    for (int r = 1; r < 8; ++r)
        if (lg[r] > mx) { mx = lg[r]; ki = kk[r]; }
    float mxo = __shfl_xor(mx, 32);
    int   kio = __shfl_xor(ki, 32);
    if (mxo > mx || (mxo == mx && kio < ki)) { mx = mxo; ki = kio; }

    float es[8], ss = 0.0f;
#pragma unroll
    for (int r = 0; r < 8; ++r) {
        es[r] = __expf(1.0e4f * (lg[r] - mx));
        ss += es[r];
    }
    ss += __shfl_xor(ss, 32);
    float inv = 1.0f / ss;

    size_t mbase = (size_t)(b*K_) << 18;
#pragma unroll
    for (int r = 0; r < 8; ++r)
        m_out[mbase + ((size_t)kk[r] << 18) + px] = es[r] * inv;

    if (half == 0) {
        labels[((size_t)b << 18) + px] = ki;
        const float* ip = img + ((size_t)(b*3) << 18) + px;
        atomicAdd(&bins[ki*4+0], ip[0]);
        atomicAdd(&bins[ki*4+1], ip[(size_t)1 << 18]);
        atomicAdd(&bins[ki*4+2], ip[(size_t)2 << 18]);
        atomicAdd(&bins[ki*4+3], 1.0f);
    }
    __syncthreads();
    // spread cross-block contention over NSLICE accumulator copies
    if (t < K_*4) atomicAdd(&accum[(blk & (NSLICE-1))*256 + b*K_*4 + t], bins[t]);
}

__global__ __launch_bounds__(64) void palette_kernel(
    const float* __restrict__ accum, int nslices,
    float* __restrict__ pal_out, float* __restrict__ palf)
{
    int t = threadIdx.x;   // b*16+k
    float s0 = 0.0f, s1 = 0.0f, s2 = 0.0f, s3 = 0.0f;
    for (int sl = 0; sl < nslices; ++sl) {
        const float* a = accum + sl*256 + t*4;
        s0 += a[0]; s1 += a[1]; s2 += a[2]; s3 += a[3];
    }
    float invd = 1.0f / (s3 + 1e-8f);
    float p0 = s0*invd, p1 = s1*invd, p2 = s2*invd;
    palf[t*3+0] = p0; pal_out[t*3+0] = p0;
    palf[t*3+1] = p1; pal_out[t*3+1] = p1;
    palf[t*3+2] = p2; pal_out[t*3+2] = p2;
}

__global__ __launch_bounds__(256) void recolor_lbl_kernel(
    const int* __restrict__ labels, const float* __restrict__ palf,
    float* __restrict__ timg)
{
    int g = blockIdx.x*256 + threadIdx.x;
    int b = g >> 18;
    int p = g & (HW_-1);
    int ks = labels[g];
#pragma unroll
    for (int c = 0; c < 3; ++c)
        timg[((size_t)(b*3+c) << 18) + p] = palf[(b*K_ + ks)*3 + c];
}

// ================= scalar fallback (known-passing) =================
__global__ __launch_bounds__(256) void prep_scalar(
    const float* __restrict__ W1, const float* __restrict__ b1,
    const float* __restrict__ W2, float* __restrict__ wsf)
{
    int t = threadIdx.x;
    wsf[t] = 0.0f;
    for (int i = t; i < HID_*C_; i += 256) wsf[256 + i] = W1[i];
    if (t < HID_) wsf[8448 + t] = b1[t];
    for (int i = t; i < K_*HID_; i += 256) {
        int k = i / HID_, o = i % HID_;
        wsf[8576 + o*K_ + k] = W2[i];
    }
}

__global__ __launch_bounds__(256) void mlp_scalar(
    const float* __restrict__ feat, const float* __restrict__ img,
    const float* __restrict__ wsf, float* __restrict__ m_out,
    float* __restrict__ accum)
{
    __shared__ float bins[K_*4];
    int t = threadIdx.x;
    if (t < K_*4) bins[t] = 0.0f;
    __syncthreads();
    int g = blockIdx.x*256 + t;
    int b = g >> 18, p = g & (HW_-1);
    const float* fp = feat + ((size_t)(b*C_) << 18) + p;
    float f[C_];
#pragma unroll
    for (int c = 0; c < C_; ++c) f[c] = fp[(size_t)c << 18];
    const float* W1f = wsf + 256;
    const float* b1f = wsf + 8448;
    const float* W2T = wsf + 8576;
    float logits[K_];
#pragma unroll
    for (int k = 0; k < K_; ++k) logits[k] = 0.0f;
    for (int o = 0; o < HID_; ++o) {
        float h = b1f[o];
#pragma unroll
        for (int c = 0; c < C_; ++c) h = fmaf(f[c], W1f[o*C_ + c], h);
        h = fmaxf(h, 0.0f);
#pragma unroll
        for (int k = 0; k < K_; ++k) logits[k] = fmaf(h, W2T[o*K_ + k], logits[k]);
    }
    float lmax = logits[0]; int kstar = 0;
#pragma unroll
    for (int k = 1; k < K_; ++k)
        if (logits[k] > lmax) { lmax = logits[k]; kstar = k; }
    float ex[K_], esum = 0.0f;
#pragma unroll
    for (int k = 0; k < K_; ++k) { ex[k] = __expf(1.0e4f*(logits[k]-lmax)); esum += ex[k]; }
    float inv = 1.0f / esum;
#pragma unroll
    for (int k = 0; k < K_; ++k)
        m_out[((size_t)(b*K_ + k) << 18) + p] = ex[k] * inv;
    const float* ip = img + ((size_t)(b*3) << 18) + p;
    atomicAdd(&bins[kstar*4+0], ip[0]);
    atomicAdd(&bins[kstar*4+1], ip[(size_t)1 << 18]);
    atomicAdd(&bins[kstar*4+2], ip[(size_t)2 << 18]);
    atomicAdd(&bins[kstar*4+3], 1.0f);
    __syncthreads();
    if (t < K_*4) atomicAdd(&accum[b*K_*4 + t], bins[t]);
}

__global__ __launch_bounds__(256) void recolor_m_kernel(
    const float* __restrict__ m_in, const float* __restrict__ palf,
    float* __restrict__ timg)
{
    int g = blockIdx.x*256 + threadIdx.x;
    int b = g >> 18, p = g & (HW_-1);
    const float* mp = m_in + ((size_t)(b*K_) << 18) + p;
    float best = -1.0f; int ks = 0;
#pragma unroll
    for (int k = 0; k < K_; ++k) {
        float v = mp[(size_t)k << 18];
        if (v > best) { best = v; ks = k; }
    }
#pragma unroll
    for (int c = 0; c < 3; ++c)
        timg[((size_t)(b*3+c) << 18) + p] = palf[(b*K_ + ks)*3 + c];
}

extern "C" void kernel_launch(void* const* d_in, const int* in_sizes, int n_in,
                              void* d_out, int out_size, void* d_ws, size_t ws_size,
                              hipStream_t stream)
{
    const float* img  = (const float*)d_in[0];
    const float* feat = (const float*)d_in[1];
    const float* W1   = (const float*)d_in[2];
    const float* b1   = (const float*)d_in[3];
    const float* W2   = (const float*)d_in[4];

    float* out0 = (float*)d_out;                  // transformed_img (B,3,H,W)
    float* out1 = out0 + (size_t)B_*3*HW_;        // m (B,K,H,W)
    float* out2 = out1 + (size_t)B_*K_*HW_;       // color_palette (B,K,3,1,1)
    float* wsf  = (float*)d_ws;

    if (ws_size >= WS_NEED_FAST) {
        const unsigned short* w1f = (const unsigned short*)((char*)d_ws + W1F_BYTE);
        const unsigned short* w2f = (const unsigned short*)((char*)d_ws + W2F_BYTE);
        int* lbl = (int*)((char*)d_ws + LBL_BYTE);
        float* palf = wsf + PALF_FLT;             // byte 8192
        prep_fast<<<48, 256, 0, stream>>>(W1, W2, wsf);
        mlp_mfma<<<NPIX/128, 256, 0, stream>>>(feat, img, b1,
                                               w1f, w2f, out1, wsf, lbl);
        palette_kernel<<<1, 64, 0, stream>>>(wsf, NSLICE, out2, palf);
        recolor_lbl_kernel<<<NPIX/256, 256, 0, stream>>>(lbl, palf, out0);
    } else {
        prep_scalar<<<1, 256, 0, stream>>>(W1, b1, W2, wsf);
        mlp_scalar<<<NPIX/256, 256, 0, stream>>>(feat, img, wsf, out1, wsf);
        palette_kernel<<<1, 64, 0, stream>>>(wsf, 1, out2, wsf + 10624);
        recolor_m_kernel<<<NPIX/256, 256, 0, stream>>>(out1, wsf + 10624, out0);
    }
}